// Round 18
// baseline (681.489 us; speedup 1.0000x reference)
//
#include <hip/hip_runtime.h>
#include <hip/hip_cooperative_groups.h>
#include <math.h>

namespace cg = cooperative_groups;

#define ROWS   8192

typedef __attribute__((ext_vector_type(8))) short v8s;
typedef __attribute__((ext_vector_type(4))) float v4f;
typedef __attribute__((ext_vector_type(8))) unsigned short v8u;

__device__ __forceinline__ unsigned short f2bf(float x) {
    unsigned int u = __float_as_uint(x);
    u += 0x7fffu + ((u >> 16) & 1u);
    return (unsigned short)(u >> 16);
}
__device__ __forceinline__ float bf2f(unsigned short x) {
    return __uint_as_float(((unsigned int)x) << 16);
}

// async global -> LDS, 16B per lane; LDS dest = wave-uniform base + lane*16
__device__ __forceinline__ void glds16(const void* g, void* l) {
    __builtin_amdgcn_global_load_lds(
        (const __attribute__((address_space(1))) unsigned int*)g,
        (__attribute__((address_space(3))) unsigned int*)l, 16, 0, 0);
}

// ---------------------------------------------------------------------------
// trans_tile: out_bf[(n_off+n)*ldout + k] = bf16(in[k*N + n])
// ---------------------------------------------------------------------------
__device__ __forceinline__ void trans_tile(const float* __restrict__ in,
                                           unsigned short* __restrict__ out,
                                           int K, int N, int ldout, int n_off,
                                           int bx, int by, int tid)
{
    __shared__ float t[32][33];
    int tx = tid & 31, ty = tid >> 5;           // 32 x 8
    int k0 = by << 5, n0 = bx << 5;
    #pragma unroll
    for (int i = 0; i < 4; i++)
        t[ty + i * 8][tx] = in[(size_t)(k0 + ty + i * 8) * N + n0 + tx];
    __syncthreads();
    #pragma unroll
    for (int i = 0; i < 4; i++)
        out[(size_t)(n_off + n0 + ty + i * 8) * ldout + k0 + tx] = f2bf(t[tx][ty + i * 8]);
}

// ---------------------------------------------------------------------------
// proj tile: BM=64/BN=128/BK=32, A fp32 (in-register f2bf), PROJ epilogue.
// ---------------------------------------------------------------------------
__device__ __forceinline__ void proj_tile(
    const float* __restrict__ Af, const unsigned short* __restrict__ Bt,
    const float* __restrict__ bias, float* __restrict__ po,
    unsigned short* __restrict__ vbf, const float* __restrict__ refp,
    float* __restrict__ oloc, int bx, int by, int tid)
{
    __shared__ __align__(16) unsigned short As[2048];
    __shared__ __align__(16) unsigned short Bs[4096];
    const int K = 256;
    const int row0 = by << 6, col0 = bx << 7;
    const int wid = tid >> 6, lane = tid & 63;
    const int wm = wid & 1, wn = wid >> 1;
    const int lr = lane & 15, kq = lane >> 4;

    v4f acc[2][4];
    #pragma unroll
    for (int i = 0; i < 2; i++)
        #pragma unroll
        for (int j = 0; j < 4; j++) acc[i][j] = (v4f){0.f, 0.f, 0.f, 0.f};

    for (int k0 = 0; k0 < K; k0 += 32) {
        int r1 = tid >> 2, kk1 = ((tid & 3) + (r1 >> 2)) & 3;
        const float* p1 = Af + (size_t)(row0 + r1) * K + k0 + kk1 * 8;
        float4 af0 = *(const float4*)p1;
        float4 af1 = *(const float4*)(p1 + 4);
        __syncthreads();
        v8u u1;
        u1[0] = f2bf(af0.x); u1[1] = f2bf(af0.y); u1[2] = f2bf(af0.z); u1[3] = f2bf(af0.w);
        u1[4] = f2bf(af1.x); u1[5] = f2bf(af1.y); u1[6] = f2bf(af1.z); u1[7] = f2bf(af1.w);
        *(v8u*)(&As[tid * 8]) = u1;
        #pragma unroll
        for (int i = 0; i < 2; i++) {
            int c = wid * 128 + i * 64 + lane;
            int row = c >> 2;
            int kk = ((c & 3) + (row >> 2)) & 3;
            glds16(Bt + (size_t)(col0 + row) * K + k0 + kk * 8,
                   &Bs[(wid * 128 + i * 64) * 8]);
        }
        __syncthreads();
        v8s bf[4];
        #pragma unroll
        for (int nt = 0; nt < 4; nt++) {
            int row = wn * 64 + nt * 16 + lr;
            int s = (kq - (row >> 2)) & 3;
            bf[nt] = *(const v8s*)(&Bs[(row * 4 + s) * 8]);
        }
        #pragma unroll
        for (int mt = 0; mt < 2; mt++) {
            int row = wm * 32 + mt * 16 + lr;
            int s = (kq - (row >> 2)) & 3;
            v8s af = *(const v8s*)(&As[(row * 4 + s) * 8]);
            #pragma unroll
            for (int nt = 0; nt < 4; nt++)
                acc[mt][nt] = __builtin_amdgcn_mfma_f32_16x16x32_bf16(af, bf[nt], acc[mt][nt], 0, 0, 0);
        }
    }

    const int rq = lane >> 4;
    #pragma unroll
    for (int mt = 0; mt < 2; mt++) {
        #pragma unroll
        for (int nt = 0; nt < 4; nt++) {
            int col = col0 + wn * 64 + nt * 16 + lr;
            float bv = bias[col];
            #pragma unroll
            for (int i = 0; i < 4; i++) {
                int row = row0 + wm * 32 + mt * 16 + rq * 4 + i;
                float v = acc[mt][nt][i] + bv;
                if (col < 256) {
                    int b = row >> 12, rb = row & 4095;
                    int l = rb >> 10, pix = rb & 1023;
                    int h = col >> 5, d = col & 31;
                    size_t idx = ((size_t)(((b << 2) + l) * 8 + h) << 15) + (pix << 5) + d;
                    vbf[idx] = f2bf(v);
                } else if (col < 512) {
                    int colm = col - 256;
                    int l = (colm >> 3) & 3, cc = colm & 1;
                    oloc[(size_t)row * 256 + colm] =
                        refp[(size_t)row * 8 + l * 2 + cc] + v * (1.f / 32.f);
                } else {
                    po[(size_t)row * 128 + col - 512] = v;
                }
            }
        }
    }
}

// ---------------------------------------------------------------------------
// FFN1 tile: BM=64/BN=128/BK=32, bf16 A via glds16, relu, bf16 out. N=1024.
// ---------------------------------------------------------------------------
__device__ __forceinline__ void ffn1_tile(
    const unsigned short* __restrict__ A, const unsigned short* __restrict__ Bt,
    const float* __restrict__ bias, unsigned short* __restrict__ Cout,
    int bx, int by, int tid)
{
    __shared__ __align__(16) unsigned short As1[2048];
    __shared__ __align__(16) unsigned short Bs1[4096];
    const int K = 256, N = 1024;
    const int row0 = by << 6, col0 = bx << 7;
    const int wid = tid >> 6, lane = tid & 63;
    const int wm = wid & 1, wn = wid >> 1;
    const int lr = lane & 15, kq = lane >> 4;

    v4f acc[2][4];
    #pragma unroll
    for (int i = 0; i < 2; i++)
        #pragma unroll
        for (int j = 0; j < 4; j++) acc[i][j] = (v4f){0.f, 0.f, 0.f, 0.f};

    for (int k0 = 0; k0 < K; k0 += 32) {
        __syncthreads();
        {
            int c = wid * 64 + lane;
            int row = c >> 2;
            int kk = ((c & 3) + (row >> 2)) & 3;
            glds16(A + (size_t)(row0 + row) * K + k0 + kk * 8, &As1[(wid * 64) * 8]);
        }
        #pragma unroll
        for (int i = 0; i < 2; i++) {
            int c = wid * 128 + i * 64 + lane;
            int row = c >> 2;
            int kk = ((c & 3) + (row >> 2)) & 3;
            glds16(Bt + (size_t)(col0 + row) * K + k0 + kk * 8,
                   &Bs1[(wid * 128 + i * 64) * 8]);
        }
        __syncthreads();
        v8s bf[4];
        #pragma unroll
        for (int nt = 0; nt < 4; nt++) {
            int row = wn * 64 + nt * 16 + lr;
            int s = (kq - (row >> 2)) & 3;
            bf[nt] = *(const v8s*)(&Bs1[(row * 4 + s) * 8]);
        }
        #pragma unroll
        for (int mt = 0; mt < 2; mt++) {
            int row = wm * 32 + mt * 16 + lr;
            int s = (kq - (row >> 2)) & 3;
            v8s af = *(const v8s*)(&As1[(row * 4 + s) * 8]);
            #pragma unroll
            for (int nt = 0; nt < 4; nt++)
                acc[mt][nt] = __builtin_amdgcn_mfma_f32_16x16x32_bf16(af, bf[nt], acc[mt][nt], 0, 0, 0);
        }
    }

    const int rq = lane >> 4;
    #pragma unroll
    for (int mt = 0; mt < 2; mt++) {
        #pragma unroll
        for (int nt = 0; nt < 4; nt++) {
            int col = col0 + wn * 64 + nt * 16 + lr;
            float bv = bias[col];
            #pragma unroll
            for (int i = 0; i < 4; i++) {
                int row = row0 + wm * 32 + mt * 16 + rq * 4 + i;
                float v = fmaxf(acc[mt][nt][i] + bv, 0.f);
                Cout[(size_t)row * N + col] = f2bf(v);
            }
        }
    }
}

// ---------------------------------------------------------------------------
// FFN2 tile: BM=64/BN=64/BK=32, K=1024, +res, fp32 out. N=256.
// ---------------------------------------------------------------------------
__device__ __forceinline__ void ffn2_tile(
    const unsigned short* __restrict__ A, const unsigned short* __restrict__ Bt,
    const float* __restrict__ bias, const float* __restrict__ res,
    float* __restrict__ Cout, int bx, int by, int tid)
{
    __shared__ __align__(16) unsigned short As2[2048];
    __shared__ __align__(16) unsigned short Bs2[2048];
    const int K = 1024, N = 256;
    const int row0 = by << 6, col0 = bx << 6;
    const int wid = tid >> 6, lane = tid & 63;
    const int lr = lane & 15, kq = lane >> 4;

    v4f acc[4];
    #pragma unroll
    for (int i = 0; i < 4; i++) acc[i] = (v4f){0.f, 0.f, 0.f, 0.f};

    for (int k0 = 0; k0 < K; k0 += 32) {
        __syncthreads();
        {
            int c = wid * 64 + lane;
            int row = c >> 2;
            int kk = ((c & 3) + (row >> 2)) & 3;
            glds16(A + (size_t)(row0 + row) * K + k0 + kk * 8, &As2[wid * 512]);
            glds16(Bt + (size_t)(col0 + row) * K + k0 + kk * 8, &Bs2[wid * 512]);
        }
        __syncthreads();
        int colr = wid * 16 + lr;
        int sb = (kq - (colr >> 2)) & 3;
        v8s bf = *(const v8s*)(&Bs2[(colr * 4 + sb) * 8]);
        #pragma unroll
        for (int mt = 0; mt < 4; mt++) {
            int rowr = mt * 16 + lr;
            int sa = (kq - (rowr >> 2)) & 3;
            v8s af = *(const v8s*)(&As2[(rowr * 4 + sa) * 8]);
            acc[mt] = __builtin_amdgcn_mfma_f32_16x16x32_bf16(af, bf, acc[mt], 0, 0, 0);
        }
    }

    const int rq = lane >> 4;
    const int col = col0 + wid * 16 + lr;
    float bv = bias[col];
    #pragma unroll
    for (int mt = 0; mt < 4; mt++) {
        #pragma unroll
        for (int i = 0; i < 4; i++) {
            int row = row0 + mt * 16 + rq * 4 + i;
            float v = acc[mt][i] + bv + res[(size_t)row * N + col];
            Cout[(size_t)row * N + col] = v;
        }
    }
}

// ---------------------------------------------------------------------------
// outproj + residual + LN1 tile: BM=32/BN=256 full-row (R15-proven).
// ---------------------------------------------------------------------------
__device__ __forceinline__ void outproj_ln_tile(
    const unsigned short* __restrict__ A, const unsigned short* __restrict__ Bt,
    const float* __restrict__ bias, const float* __restrict__ res,
    const float* __restrict__ g, const float* __restrict__ b,
    float* __restrict__ out, unsigned short* __restrict__ outbf,
    int bxy, int tid)
{
    __shared__ __align__(16) unsigned short As3[1024];
    __shared__ __align__(16) unsigned short Bs3[8192];
    __shared__ float red[2][32][4];
    const int K = 256;
    const int row0 = bxy << 5;
    const int wid = tid >> 6, lane = tid & 63;
    const int lr = lane & 15, kq = lane >> 4;
    const int rq = kq;

    v4f acc[2][4];
    #pragma unroll
    for (int i = 0; i < 2; i++)
        #pragma unroll
        for (int j = 0; j < 4; j++) acc[i][j] = (v4f){0.f, 0.f, 0.f, 0.f};

    for (int k0 = 0; k0 < K; k0 += 32) {
        __syncthreads();
        if (wid < 2) {
            int c = wid * 64 + lane;
            int row = c >> 2;
            int kk = ((c & 3) + (row >> 2)) & 3;
            glds16(A + (size_t)(row0 + row) * K + k0 + kk * 8, &As3[(wid * 64) * 8]);
        }
        #pragma unroll
        for (int i = 0; i < 4; i++) {
            int c = (wid * 4 + i) * 64 + lane;
            int col = c >> 2;
            int kk = ((c & 3) + (col >> 2)) & 3;
            glds16(Bt + (size_t)col * K + k0 + kk * 8, &Bs3[((wid * 4 + i) * 64) * 8]);
        }
        __syncthreads();
        v8s bf[4];
        #pragma unroll
        for (int ct = 0; ct < 4; ct++) {
            int col = wid * 64 + ct * 16 + lr;
            int s = (kq - (col >> 2)) & 3;
            bf[ct] = *(const v8s*)(&Bs3[(col * 4 + s) * 8]);
        }
        #pragma unroll
        for (int rt = 0; rt < 2; rt++) {
            int rowl = rt * 16 + lr;
            int s = (kq - (rowl >> 2)) & 3;
            v8s af = *(const v8s*)(&As3[(rowl * 4 + s) * 8]);
            #pragma unroll
            for (int ct = 0; ct < 4; ct++)
                acc[rt][ct] = __builtin_amdgcn_mfma_f32_16x16x32_bf16(af, bf[ct], acc[rt][ct], 0, 0, 0);
        }
    }

    float t[2][4][4];
    float s1[2][4], s2[2][4];
    #pragma unroll
    for (int rt = 0; rt < 2; rt++)
        #pragma unroll
        for (int i = 0; i < 4; i++) { s1[rt][i] = 0.f; s2[rt][i] = 0.f; }
    #pragma unroll
    for (int rt = 0; rt < 2; rt++) {
        #pragma unroll
        for (int ct = 0; ct < 4; ct++) {
            int col = wid * 64 + ct * 16 + lr;
            float bv = bias[col];
            #pragma unroll
            for (int i = 0; i < 4; i++) {
                int row = row0 + rt * 16 + rq * 4 + i;
                float v = acc[rt][ct][i] + bv + res[(size_t)row * 256 + col];
                t[rt][ct][i] = v;
                s1[rt][i] += v;
                s2[rt][i] += v * v;
            }
        }
    }
    #pragma unroll
    for (int o = 1; o < 16; o <<= 1) {
        #pragma unroll
        for (int rt = 0; rt < 2; rt++)
            #pragma unroll
            for (int i = 0; i < 4; i++) {
                s1[rt][i] += __shfl_xor(s1[rt][i], o);
                s2[rt][i] += __shfl_xor(s2[rt][i], o);
            }
    }
    if (lr == 0) {
        #pragma unroll
        for (int rt = 0; rt < 2; rt++)
            #pragma unroll
            for (int i = 0; i < 4; i++) {
                int rl = rt * 16 + rq * 4 + i;
                red[0][rl][wid] = s1[rt][i];
                red[1][rl][wid] = s2[rt][i];
            }
    }
    __syncthreads();
    float mu[2][4], rstd[2][4];
    #pragma unroll
    for (int rt = 0; rt < 2; rt++) {
        #pragma unroll
        for (int i = 0; i < 4; i++) {
            int rl = rt * 16 + rq * 4 + i;
            float S1 = red[0][rl][0] + red[0][rl][1] + red[0][rl][2] + red[0][rl][3];
            float S2 = red[1][rl][0] + red[1][rl][1] + red[1][rl][2] + red[1][rl][3];
            float m = S1 * (1.f / 256.f);
            mu[rt][i] = m;
            rstd[rt][i] = rsqrtf(S2 * (1.f / 256.f) - m * m + 1e-5f);
        }
    }
    #pragma unroll
    for (int rt = 0; rt < 2; rt++) {
        #pragma unroll
        for (int ct = 0; ct < 4; ct++) {
            int col = wid * 64 + ct * 16 + lr;
            float gg = g[col], bb = b[col];
            #pragma unroll
            for (int i = 0; i < 4; i++) {
                int row = row0 + rt * 16 + rq * 4 + i;
                float o = (t[rt][ct][i] - mu[rt][i]) * rstd[rt][i] * gg + bb;
                out[(size_t)row * 256 + col] = o;
                outbf[(size_t)row * 256 + col] = f2bf(o);
            }
        }
    }
}

// ---------------------------------------------------------------------------
// LN2 rows (4 rows per call)
// ---------------------------------------------------------------------------
__device__ __forceinline__ void ln_rows(float* __restrict__ x,
                                        const float* __restrict__ g,
                                        const float* __restrict__ b,
                                        int t, int tid)
{
    int lane = tid & 63;
    int wv = tid >> 6;
    int row = t * 4 + wv;
    int c = lane << 2;
    float4 v = *(const float4*)(x + (size_t)row * 256 + c);
    float s = v.x + v.y + v.z + v.w;
    #pragma unroll
    for (int o = 1; o < 64; o <<= 1) s += __shfl_xor(s, o);
    float mu = s * (1.f / 256.f);
    float d0 = v.x - mu, d1 = v.y - mu, d2 = v.z - mu, d3 = v.w - mu;
    float vs = d0 * d0 + d1 * d1 + d2 * d2 + d3 * d3;
    #pragma unroll
    for (int o = 1; o < 64; o <<= 1) vs += __shfl_xor(vs, o);
    float rstd = rsqrtf(vs * (1.f / 256.f) + 1e-5f);
    float4 gg = *(const float4*)(g + c);
    float4 bb = *(const float4*)(b + c);
    float4 o4;
    o4.x = d0 * rstd * gg.x + bb.x;
    o4.y = d1 * rstd * gg.y + bb.y;
    o4.z = d2 * rstd * gg.z + bb.z;
    o4.w = d3 * rstd * gg.w + bb.w;
    *(float4*)(x + (size_t)row * 256 + c) = o4;
}

// ---------------------------------------------------------------------------
// coopA: prep (737 tasks) -> grid.sync -> proj (640 tiles). 512 blocks.
// ---------------------------------------------------------------------------
__global__ __launch_bounds__(256, 2) void coopA_k(
    const float* src,
    const float* vw, const float* ofw, const float* aww, const float* pw,
    const float* w1, const float* w2,
    unsigned short* Btcat, unsigned short* pwT,
    unsigned short* w1T, unsigned short* w2T,
    const float* vb, const float* ofb, const float* awb, float* biascat,
    float* po, unsigned short* vbf, const float* refp, float* oloc)
{
    int bid = blockIdx.x, tid = threadIdx.x;
    for (int t = bid; t < 737; t += 512) {
        if (t < 64) { trans_tile(vw, Btcat, 256, 256, 256, 0, t & 7, t >> 3, tid); }
        else if (t < 128) { int u = t - 64;  trans_tile(ofw, Btcat, 256, 256, 256, 256, u & 7, u >> 3, tid); }
        else if (t < 160) { int u = t - 128; trans_tile(aww, Btcat, 256, 128, 256, 512, u & 3, u >> 2, tid); }
        else if (t < 224) { int u = t - 160; trans_tile(pw, pwT, 256, 256, 256, 0, u & 7, u >> 3, tid); }
        else if (t < 480) { int u = t - 224; trans_tile(w1, w1T, 256, 1024, 256, 0, u & 31, u >> 5, tid); }
        else if (t < 736) { int u = t - 480; trans_tile(w2, w2T, 1024, 256, 1024, 0, u & 7, u >> 3, tid); }
        else {
            biascat[tid] = vb[tid];
            biascat[tid + 256] = ofb[tid];
            if (tid < 128) biascat[tid + 512] = awb[tid];
        }
        __syncthreads();
    }
    __threadfence();
    cg::this_grid().sync();
    for (int t = bid; t < 640; t += 512)
        proj_tile(src, Btcat, biascat, po, vbf, refp, oloc, t % 5, t / 5, tid);
}

// ---------------------------------------------------------------------------
// coopC: outproj+LN1 -> FFN1 -> FFN2 -> LN2. 512 blocks.
// ---------------------------------------------------------------------------
__global__ __launch_bounds__(256, 2) void coopC_k(
    const unsigned short* attn_bf, const unsigned short* pwT, const float* pb,
    const float* src, const float* g1, const float* b1,
    float* x1, unsigned short* x1_bf,
    const unsigned short* w1T, const float* bi1, unsigned short* hidden_bf,
    const unsigned short* w2T, const float* bi2, float* out_x,
    const float* g2, const float* b2)
{
    int bid = blockIdx.x, tid = threadIdx.x;
    if (bid < 256)
        outproj_ln_tile(attn_bf, pwT, pb, src, g1, b1, x1, x1_bf, bid, tid);
    __threadfence();
    cg::this_grid().sync();
    for (int t = bid; t < 1024; t += 512)
        ffn1_tile(x1_bf, w1T, bi1, hidden_bf, t % 8, t / 8, tid);
    __threadfence();
    cg::this_grid().sync();
    ffn2_tile(hidden_bf, w2T, bi2, x1, out_x, bid % 4, bid / 4, tid);
    __threadfence();
    cg::this_grid().sync();
    for (int t = bid; t < 2048; t += 512)
        ln_rows(out_x, g2, b2, t, tid);
}

// ---------------------------------------------------------------------------
// Fused gather, level-split, 16B taps (R16-proven). XCD-aware h.
// ---------------------------------------------------------------------------
__global__ __launch_bounds__(256) void fused_gather_k(
    const float* __restrict__ po,              // [ROWS][128] logits
    const unsigned short* __restrict__ vbf,    // [64][1024][32] bf16
    const float* __restrict__ loc,             // [ROWS][256] sampling locs
    unsigned short* __restrict__ attn_bf)      // [ROWS][256] bf16
{
    int tid = threadIdx.x;
    int g = tid >> 4, l = (tid >> 2) & 3, d8 = tid & 3;
    int h = blockIdx.x & 7;                    // XCD-aligned head
    int r = (blockIdx.x >> 3) * 16 + g;
    int b = r >> 12;

    float locv[8];
    *(float4*)(locv)     = *(const float4*)(loc + (size_t)r * 256 + h * 32 + l * 8);
    *(float4*)(locv + 4) = *(const float4*)(loc + (size_t)r * 256 + h * 32 + l * 8 + 4);

    float w4[4];
    *(float4*)(w4) = *(const float4*)(po + (size_t)r * 128 + h * 16 + l * 4);
    float m = fmaxf(fmaxf(w4[0], w4[1]), fmaxf(w4[2], w4[3]));
    m = fmaxf(m, __shfl_xor(m, 4));
    m = fmaxf(m, __shfl_xor(m, 8));
    float s = 0.f;
    #pragma unroll
    for (int p = 0; p < 4; p++) { w4[p] = __expf(w4[p] - m); s += w4[p]; }
    s += __shfl_xor(s, 4);
    s += __shfl_xor(s, 8);
    float inv = 1.f / s;

    const unsigned short* vbase =
        vbf + (((size_t)(((b << 2) + l) * 8 + h)) << 15) + d8 * 8;

    float acc[8];
    #pragma unroll
    for (int k = 0; k < 8; k++) acc[k] = 0.f;

    #pragma unroll
    for (int pp = 0; pp < 2; pp++) {
        v8u uv[8];
        float cw[8];
        #pragma unroll
        for (int p2 = 0; p2 < 2; p2++) {
            int p = pp * 2 + p2;
            float xf = locv[p * 2] * 32.f - 0.5f, yf = locv[p * 2 + 1] * 32.f - 0.5f;
            float x0f = floorf(xf), y0f = floorf(yf);
            float fx = xf - x0f, fy = yf - y0f;
            int x0 = (int)x0f, y0 = (int)y0f;
            float wgt = w4[p] * inv;
            #pragma unroll
            for (int dy = 0; dy < 2; dy++) {
                #pragma unroll
                for (int dx = 0; dx < 2; dx++) {
                    int idx = p2 * 4 + dy * 2 + dx;
                    int xi = x0 + dx, yi = y0 + dy;
                    float wt = (dx ? fx : 1.f - fx) * (dy ? fy : 1.f - fy);
                    bool valid = (xi >= 0) & (xi < 32) & (yi >= 0) & (yi < 32);
                    int xc = min(max(xi, 0), 31), yc = min(max(yi, 0), 31);
                    cw[idx] = valid ? (wgt * wt) : 0.f;
                    uv[idx] = *(const v8u*)(vbase + (size_t)((yc << 5) + xc) * 32);
                }
            }
        }
        #pragma unroll
        for (int idx = 0; idx < 8; idx++) {
            float c = cw[idx];
            #pragma unroll
            for (int k = 0; k < 8; k++)
                acc[k] += c * bf2f(uv[idx][k]);
        }
    }
    #pragma unroll
    for (int k = 0; k < 8; k++) {
        acc[k] += __shfl_xor(acc[k], 4);
        acc[k] += __shfl_xor(acc[k], 8);
    }
    if (l == 0) {
        v8u o;
        #pragma unroll
        for (int k = 0; k < 8; k++) o[k] = f2bf(acc[k]);
        *(v8u*)(attn_bf + (size_t)r * 256 + h * 32 + d8 * 8) = o;
    }
}

// ---------------------------------------------------------------------------
extern "C" void kernel_launch(void* const* d_in, const int* in_sizes, int n_in,
                              void* d_out, int out_size, void* d_ws, size_t ws_size,
                              hipStream_t stream)
{
    const float* src   = (const float*)d_in[0];
    const float* refp  = (const float*)d_in[2];
    const float* vw    = (const float*)d_in[3];
    const float* vb    = (const float*)d_in[4];
    const float* ofw   = (const float*)d_in[5];
    const float* ofb   = (const float*)d_in[6];
    const float* aww   = (const float*)d_in[7];
    const float* awb   = (const float*)d_in[8];
    const float* pw    = (const float*)d_in[9];
    const float* pb    = (const float*)d_in[10];
    const float* g1    = (const float*)d_in[11];
    const float* b1    = (const float*)d_in[12];
    const float* w1    = (const float*)d_in[13];
    const float* bi1   = (const float*)d_in[14];
    const float* w2    = (const float*)d_in[15];
    const float* bi2   = (const float*)d_in[16];
    const float* g2    = (const float*)d_in[17];
    const float* b2    = (const float*)d_in[18];

    float* ws = (float*)d_ws;
    float*          po        = ws;                               // 1,048,576 f
    float*          x1        = ws + 1048576;                     // 2,097,152 f
    unsigned short* value_bf  = (unsigned short*)(ws + 3145728);  // 2,097,152 us
    unsigned short* x1_bf     = (unsigned short*)(ws + 5242880);
    unsigned short* attn_bf   = (unsigned short*)(ws + 6291456);
    unsigned short* hidden_bf = (unsigned short*)(ws + 7340032);  // 8,388,608 us
    unsigned short* Btcat     = (unsigned short*)(ws + 11534336); // 163,840 us
    unsigned short* pwT       = (unsigned short*)(ws + 11616256);
    unsigned short* w1T       = (unsigned short*)(ws + 11649024);
    unsigned short* w2T       = (unsigned short*)(ws + 11780096);
    float*          biascat   = ws + 11911168;                    // 640 f

    float* out_x   = (float*)d_out;
    float* out_loc = out_x + 2097152;

    // --- coopA: prep + proj ---
    void* argsA[] = {
        (void*)&src, (void*)&vw, (void*)&ofw, (void*)&aww, (void*)&pw,
        (void*)&w1, (void*)&w2, (void*)&Btcat, (void*)&pwT, (void*)&w1T,
        (void*)&w2T, (void*)&vb, (void*)&ofb, (void*)&awb, (void*)&biascat,
        (void*)&po, (void*)&value_bf, (void*)&refp, (void*)&out_loc
    };
    hipLaunchCooperativeKernel((const void*)coopA_k, dim3(512), dim3(256),
                               argsA, 0, stream);

    // --- softmax + deformable gather -> attn_bf
    fused_gather_k<<<4096, dim3(256), 0, stream>>>(po, value_bf, out_loc, attn_bf);

    // --- coopC: outproj+LN1 -> FFN1 -> FFN2 -> LN2 ---
    void* argsC[] = {
        (void*)&attn_bf, (void*)&pwT, (void*)&pb, (void*)&src, (void*)&g1,
        (void*)&b1, (void*)&x1, (void*)&x1_bf, (void*)&w1T, (void*)&bi1,
        (void*)&hidden_bf, (void*)&w2T, (void*)&bi2, (void*)&out_x,
        (void*)&g2, (void*)&b2
    };
    hipLaunchCooperativeKernel((const void*)coopC_k, dim3(512), dim3(256),
                               argsC, 0, stream);
}

// Round 19
// 181.929 us; speedup vs baseline: 3.7459x; 3.7459x over previous
//
#include <hip/hip_runtime.h>
#include <math.h>

#define ROWS   8192
#define LQ     4096
#define NHEAD  8
#define NLVL   4
#define NPTS   4
#define HDIM   32

typedef __attribute__((ext_vector_type(8))) short v8s;
typedef __attribute__((ext_vector_type(4))) float v4f;
typedef __attribute__((ext_vector_type(8))) unsigned short v8u;

__device__ __forceinline__ unsigned short f2bf(float x) {
    unsigned int u = __float_as_uint(x);
    u += 0x7fffu + ((u >> 16) & 1u);
    return (unsigned short)(u >> 16);
}
__device__ __forceinline__ float bf2f(unsigned short x) {
    return __uint_as_float(((unsigned int)x) << 16);
}

// async global -> LDS, 16B per lane; LDS dest = wave-uniform base + lane*16
__device__ __forceinline__ void glds16(const void* g, void* l) {
    __builtin_amdgcn_global_load_lds(
        (const __attribute__((address_space(1))) unsigned int*)g,
        (__attribute__((address_space(3))) unsigned int*)l, 16, 0, 0);
}

// ---------------------------------------------------------------------------
// Prep: weight transposes + biascat.
// ---------------------------------------------------------------------------
__device__ __forceinline__ void trans_tile(const float* __restrict__ in,
                                           unsigned short* __restrict__ out,
                                           int K, int N, int ldout, int n_off,
                                           int bx, int by, int tid)
{
    __shared__ float t[32][33];
    int tx = tid & 31, ty = tid >> 5;           // 32 x 8
    int k0 = by << 5, n0 = bx << 5;
    #pragma unroll
    for (int i = 0; i < 4; i++)
        t[ty + i * 8][tx] = in[(size_t)(k0 + ty + i * 8) * N + n0 + tx];
    __syncthreads();
    #pragma unroll
    for (int i = 0; i < 4; i++)
        out[(size_t)(n_off + n0 + ty + i * 8) * ldout + k0 + tx] = f2bf(t[tx][ty + i * 8]);
}

__global__ __launch_bounds__(256) void prep_k(
    const float* __restrict__ vw, const float* __restrict__ ofw,
    const float* __restrict__ aww, const float* __restrict__ pw,
    const float* __restrict__ w1, const float* __restrict__ w2,
    unsigned short* __restrict__ Btcat, unsigned short* __restrict__ pwT,
    unsigned short* __restrict__ w1T, unsigned short* __restrict__ w2T,
    const float* __restrict__ vb, const float* __restrict__ ofb,
    const float* __restrict__ awb, float* __restrict__ biascat)
{
    int bid = blockIdx.x, tid = threadIdx.x;
    if (bid < 64) {                              // vw: 8x8
        int t = bid; trans_tile(vw, Btcat, 256, 256, 256, 0, t & 7, t >> 3, tid);
    } else if (bid < 128) {                      // ofw: 8x8
        int t = bid - 64; trans_tile(ofw, Btcat, 256, 256, 256, 256, t & 7, t >> 3, tid);
    } else if (bid < 160) {                      // aww: 4x8
        int t = bid - 128; trans_tile(aww, Btcat, 256, 128, 256, 512, t & 3, t >> 2, tid);
    } else if (bid < 224) {                      // pw: 8x8
        int t = bid - 160; trans_tile(pw, pwT, 256, 256, 256, 0, t & 7, t >> 3, tid);
    } else if (bid < 480) {                      // w1: 32x8
        int t = bid - 224; trans_tile(w1, w1T, 256, 1024, 256, 0, t & 31, t >> 5, tid);
    } else if (bid < 736) {                      // w2: 8x32
        int t = bid - 480; trans_tile(w2, w2T, 1024, 256, 1024, 0, t & 7, t >> 3, tid);
    } else {                                     // biascat
        biascat[tid] = vb[tid];
        biascat[tid + 256] = ofb[tid];
        if (tid < 128) biascat[tid + 512] = awb[tid];
    }
}

// ---------------------------------------------------------------------------
// bf16 MFMA GEMM, BM=64/BN=128/BK=32. XOR-swizzled glds16 LDS.
// AF32: A fp32 staged with in-register f2bf (1 chunk/thread).
// PROJ (N=640): [0,256) -> compact value bf16; [256,512) -> out_loc;
// [512,640) -> po logits.
// ---------------------------------------------------------------------------
template<bool PROJ, bool AF32, bool OUTBF, bool RELU, bool RES>
__global__ __launch_bounds__(256) void mfma_gemm128_k(
    const void* __restrict__ Araw,          // bf16 or fp32 [M][K]
    const unsigned short* __restrict__ Bt,  // bf16 [N][K]
    const float* __restrict__ bias,
    const float* __restrict__ res,
    void* __restrict__ Cout,
    unsigned short* __restrict__ vbf,       // PROJ only
    const float* __restrict__ refp,         // PROJ only
    float* __restrict__ oloc,               // PROJ only
    int M, int N, int K)
{
    __shared__ __align__(16) unsigned short As[2048];   // 256 chunks x 16B
    __shared__ __align__(16) unsigned short Bs[4096];   // 512 chunks x 16B
    const int tid = threadIdx.x;
    const int row0 = blockIdx.y << 6, col0 = blockIdx.x << 7;
    const int wid = tid >> 6, lane = tid & 63;
    const int wm = wid & 1, wn = wid >> 1;
    const int lr = lane & 15, kq = lane >> 4;

    v4f acc[2][4];
    #pragma unroll
    for (int i = 0; i < 2; i++)
        #pragma unroll
        for (int j = 0; j < 4; j++) acc[i][j] = (v4f){0.f, 0.f, 0.f, 0.f};

    for (int k0 = 0; k0 < K; k0 += 32) {
        float4 af0, af1;
        if constexpr (AF32) {
            const float* Af = (const float*)Araw;
            int r1 = tid >> 2, kk1 = ((tid & 3) + (r1 >> 2)) & 3;
            const float* p1 = Af + (size_t)(row0 + r1) * K + k0 + kk1 * 8;
            af0 = *(const float4*)p1; af1 = *(const float4*)(p1 + 4);
        }
        __syncthreads();
        if constexpr (AF32) {
            v8u u1;
            u1[0] = f2bf(af0.x); u1[1] = f2bf(af0.y); u1[2] = f2bf(af0.z); u1[3] = f2bf(af0.w);
            u1[4] = f2bf(af1.x); u1[5] = f2bf(af1.y); u1[6] = f2bf(af1.z); u1[7] = f2bf(af1.w);
            *(v8u*)(&As[tid * 8]) = u1;
        } else {
            const unsigned short* A = (const unsigned short*)Araw;
            int c = wid * 64 + lane;
            int row = c >> 2;
            int kk = ((c & 3) + (row >> 2)) & 3;
            glds16(A + (size_t)(row0 + row) * K + k0 + kk * 8,
                   &As[(wid * 64) * 8]);
        }
        #pragma unroll
        for (int i = 0; i < 2; i++) {
            int c = wid * 128 + i * 64 + lane;
            int row = c >> 2;
            int kk = ((c & 3) + (row >> 2)) & 3;
            glds16(Bt + (size_t)(col0 + row) * K + k0 + kk * 8,
                   &Bs[(wid * 128 + i * 64) * 8]);
        }
        __syncthreads();
        v8s bf[4];
        #pragma unroll
        for (int nt = 0; nt < 4; nt++) {
            int row = wn * 64 + nt * 16 + lr;
            int s = (kq - (row >> 2)) & 3;
            bf[nt] = *(const v8s*)(&Bs[(row * 4 + s) * 8]);
        }
        #pragma unroll
        for (int mt = 0; mt < 2; mt++) {
            int row = wm * 32 + mt * 16 + lr;
            int s = (kq - (row >> 2)) & 3;
            v8s af = *(const v8s*)(&As[(row * 4 + s) * 8]);
            #pragma unroll
            for (int nt = 0; nt < 4; nt++)
                acc[mt][nt] = __builtin_amdgcn_mfma_f32_16x16x32_bf16(af, bf[nt], acc[mt][nt], 0, 0, 0);
        }
    }

    const int rq = lane >> 4;
    #pragma unroll
    for (int mt = 0; mt < 2; mt++) {
        #pragma unroll
        for (int nt = 0; nt < 4; nt++) {
            int col = col0 + wn * 64 + nt * 16 + lr;
            float bv = bias[col];
            #pragma unroll
            for (int i = 0; i < 4; i++) {
                int row = row0 + wm * 32 + mt * 16 + rq * 4 + i;
                float v = acc[mt][nt][i] + bv;
                if (RELU) v = fmaxf(v, 0.f);
                if (RES)  v += res[(size_t)row * N + col];
                if (PROJ) {
                    if (col < 256) {
                        int b = row >> 12, rb = row & 4095;
                        int l = rb >> 10, pix = rb & 1023;
                        int h = col >> 5, d = col & 31;
                        size_t idx = ((size_t)(((b << 2) + l) * 8 + h) << 15) + (pix << 5) + d;
                        vbf[idx] = f2bf(v);
                    } else if (col < 512) {
                        int colm = col - 256;
                        int l = (colm >> 3) & 3, cc = colm & 1;
                        oloc[(size_t)row * 256 + colm] =
                            refp[(size_t)row * 8 + l * 2 + cc] + v * (1.f / 32.f);
                    } else {
                        ((float*)Cout)[(size_t)row * 128 + col - 512] = v;
                    }
                } else if (OUTBF) {
                    ((unsigned short*)Cout)[(size_t)row * N + col] = f2bf(v);
                } else {
                    ((float*)Cout)[(size_t)row * N + col] = v;
                }
            }
        }
    }
}

// ---------------------------------------------------------------------------
// bf16 MFMA GEMM, BM=64/BN=64/BK=32 — FFN2 (N=256), 512 blocks (2/CU).
// ---------------------------------------------------------------------------
template<bool OUTBF, bool RELU, bool RES>
__global__ __launch_bounds__(256) void mfma_gemm64_k(
    const unsigned short* __restrict__ A,   // bf16 [M][K]
    const unsigned short* __restrict__ Bt,  // bf16 [N][K]
    const float* __restrict__ bias,
    const float* __restrict__ res,
    void* __restrict__ Cout,
    int M, int N, int K)
{
    __shared__ __align__(16) unsigned short As[2048];   // 256 chunks x 16B
    __shared__ __align__(16) unsigned short Bs[2048];   // 256 chunks x 16B
    const int tid = threadIdx.x;
    const int row0 = blockIdx.y << 6, col0 = blockIdx.x << 6;
    const int wid = tid >> 6, lane = tid & 63;
    const int lr = lane & 15, kq = lane >> 4;

    v4f acc[4];
    #pragma unroll
    for (int i = 0; i < 4; i++) acc[i] = (v4f){0.f, 0.f, 0.f, 0.f};

    for (int k0 = 0; k0 < K; k0 += 32) {
        __syncthreads();
        {
            int c = wid * 64 + lane;
            int row = c >> 2;
            int kk = ((c & 3) + (row >> 2)) & 3;
            glds16(A + (size_t)(row0 + row) * K + k0 + kk * 8, &As[wid * 512]);
            glds16(Bt + (size_t)(col0 + row) * K + k0 + kk * 8, &Bs[wid * 512]);
        }
        __syncthreads();
        int colr = wid * 16 + lr;
        int sb = (kq - (colr >> 2)) & 3;
        v8s bf = *(const v8s*)(&Bs[(colr * 4 + sb) * 8]);
        #pragma unroll
        for (int mt = 0; mt < 4; mt++) {
            int rowr = mt * 16 + lr;
            int sa = (kq - (rowr >> 2)) & 3;
            v8s af = *(const v8s*)(&As[(rowr * 4 + sa) * 8]);
            acc[mt] = __builtin_amdgcn_mfma_f32_16x16x32_bf16(af, bf, acc[mt], 0, 0, 0);
        }
    }

    const int rq = lane >> 4;
    const int col = col0 + wid * 16 + lr;
    float bv = bias[col];
    #pragma unroll
    for (int mt = 0; mt < 4; mt++) {
        #pragma unroll
        for (int i = 0; i < 4; i++) {
            int row = row0 + mt * 16 + rq * 4 + i;
            float v = acc[mt][i] + bv;
            if (RELU) v = fmaxf(v, 0.f);
            if (RES)  v += res[(size_t)row * N + col];
            if (OUTBF) ((unsigned short*)Cout)[(size_t)row * N + col] = f2bf(v);
            else       ((float*)Cout)[(size_t)row * N + col] = v;
        }
    }
}

// ---------------------------------------------------------------------------
// Full-row GEMM + residual + LayerNorm fused epilogue (outproj; R15-proven).
// ---------------------------------------------------------------------------
template<bool WRITE_BF>
__global__ __launch_bounds__(256) void mfma_gemm_ln_k(
    const unsigned short* __restrict__ A,   // bf16 [M][K]
    const unsigned short* __restrict__ Bt,  // bf16 [256][K]
    const float* __restrict__ bias,         // [256]
    const float* __restrict__ res,          // [M][256] fp32
    const float* __restrict__ g,
    const float* __restrict__ b,
    float* __restrict__ out,                // [M][256] fp32 post-LN
    unsigned short* __restrict__ outbf,     // optional bf16 post-LN
    int M, int K)
{
    __shared__ __align__(16) unsigned short As[1024];   // 128 chunks x 16B
    __shared__ __align__(16) unsigned short Bs[8192];   // 1024 chunks x 16B
    __shared__ float red[2][32][4];
    const int tid = threadIdx.x;
    const int row0 = blockIdx.x << 5;
    const int wid = tid >> 6, lane = tid & 63;
    const int lr = lane & 15, kq = lane >> 4;
    const int rq = kq;

    v4f acc[2][4];
    #pragma unroll
    for (int i = 0; i < 2; i++)
        #pragma unroll
        for (int j = 0; j < 4; j++) acc[i][j] = (v4f){0.f, 0.f, 0.f, 0.f};

    for (int k0 = 0; k0 < K; k0 += 32) {
        __syncthreads();
        if (wid < 2) {                          // A: 128 chunks
            int c = wid * 64 + lane;
            int row = c >> 2;
            int kk = ((c & 3) + (row >> 2)) & 3;
            glds16(A + (size_t)(row0 + row) * K + k0 + kk * 8,
                   &As[(wid * 64) * 8]);
        }
        #pragma unroll
        for (int i = 0; i < 4; i++) {           // B: 1024 chunks
            int c = (wid * 4 + i) * 64 + lane;
            int col = c >> 2;
            int kk = ((c & 3) + (col >> 2)) & 3;
            glds16(Bt + (size_t)col * K + k0 + kk * 8,
                   &Bs[((wid * 4 + i) * 64) * 8]);
        }
        __syncthreads();
        v8s bf[4];
        #pragma unroll
        for (int ct = 0; ct < 4; ct++) {
            int col = wid * 64 + ct * 16 + lr;
            int s = (kq - (col >> 2)) & 3;
            bf[ct] = *(const v8s*)(&Bs[(col * 4 + s) * 8]);
        }
        #pragma unroll
        for (int rt = 0; rt < 2; rt++) {
            int rowl = rt * 16 + lr;
            int s = (kq - (rowl >> 2)) & 3;
            v8s af = *(const v8s*)(&As[(rowl * 4 + s) * 8]);
            #pragma unroll
            for (int ct = 0; ct < 4; ct++)
                acc[rt][ct] = __builtin_amdgcn_mfma_f32_16x16x32_bf16(af, bf[ct], acc[rt][ct], 0, 0, 0);
        }
    }

    float t[2][4][4];
    float s1[2][4], s2[2][4];
    #pragma unroll
    for (int rt = 0; rt < 2; rt++)
        #pragma unroll
        for (int i = 0; i < 4; i++) { s1[rt][i] = 0.f; s2[rt][i] = 0.f; }
    #pragma unroll
    for (int rt = 0; rt < 2; rt++) {
        #pragma unroll
        for (int ct = 0; ct < 4; ct++) {
            int col = wid * 64 + ct * 16 + lr;
            float bv = bias[col];
            #pragma unroll
            for (int i = 0; i < 4; i++) {
                int row = row0 + rt * 16 + rq * 4 + i;
                float v = acc[rt][ct][i] + bv + res[(size_t)row * 256 + col];
                t[rt][ct][i] = v;
                s1[rt][i] += v;
                s2[rt][i] += v * v;
            }
        }
    }
    #pragma unroll
    for (int o = 1; o < 16; o <<= 1) {
        #pragma unroll
        for (int rt = 0; rt < 2; rt++)
            #pragma unroll
            for (int i = 0; i < 4; i++) {
                s1[rt][i] += __shfl_xor(s1[rt][i], o);
                s2[rt][i] += __shfl_xor(s2[rt][i], o);
            }
    }
    if (lr == 0) {
        #pragma unroll
        for (int rt = 0; rt < 2; rt++)
            #pragma unroll
            for (int i = 0; i < 4; i++) {
                int rl = rt * 16 + rq * 4 + i;
                red[0][rl][wid] = s1[rt][i];
                red[1][rl][wid] = s2[rt][i];
            }
    }
    __syncthreads();
    float mu[2][4], rstd[2][4];
    #pragma unroll
    for (int rt = 0; rt < 2; rt++) {
        #pragma unroll
        for (int i = 0; i < 4; i++) {
            int rl = rt * 16 + rq * 4 + i;
            float S1 = red[0][rl][0] + red[0][rl][1] + red[0][rl][2] + red[0][rl][3];
            float S2 = red[1][rl][0] + red[1][rl][1] + red[1][rl][2] + red[1][rl][3];
            float m = S1 * (1.f / 256.f);
            mu[rt][i] = m;
            rstd[rt][i] = rsqrtf(S2 * (1.f / 256.f) - m * m + 1e-5f);
        }
    }
    #pragma unroll
    for (int rt = 0; rt < 2; rt++) {
        #pragma unroll
        for (int ct = 0; ct < 4; ct++) {
            int col = wid * 64 + ct * 16 + lr;
            float gg = g[col], bb = b[col];
            #pragma unroll
            for (int i = 0; i < 4; i++) {
                int row = row0 + rt * 16 + rq * 4 + i;
                float o = (t[rt][ct][i] - mu[rt][i]) * rstd[rt][i] * gg + bb;
                out[(size_t)row * 256 + col] = o;
                if (WRITE_BF) outbf[(size_t)row * 256 + col] = f2bf(o);
            }
        }
    }
}

// ---------------------------------------------------------------------------
// Fused gather, level-split, 16B taps (R16-proven). XCD-aware h.
// ---------------------------------------------------------------------------
__global__ __launch_bounds__(256) void fused_gather_k(
    const float* __restrict__ po,              // [ROWS][128] logits
    const unsigned short* __restrict__ vbf,    // [64][1024][32] bf16
    const float* __restrict__ loc,             // [ROWS][256] sampling locs
    unsigned short* __restrict__ attn_bf)      // [ROWS][256] bf16
{
    int tid = threadIdx.x;
    int g = tid >> 4, l = (tid >> 2) & 3, d8 = tid & 3;
    int h = blockIdx.x & 7;                    // XCD-aligned head
    int r = (blockIdx.x >> 3) * 16 + g;
    int b = r >> 12;

    float locv[8];
    *(float4*)(locv)     = *(const float4*)(loc + (size_t)r * 256 + h * 32 + l * 8);
    *(float4*)(locv + 4) = *(const float4*)(loc + (size_t)r * 256 + h * 32 + l * 8 + 4);

    float w4[4];
    *(float4*)(w4) = *(const float4*)(po + (size_t)r * 128 + h * 16 + l * 4);
    float m = fmaxf(fmaxf(w4[0], w4[1]), fmaxf(w4[2], w4[3]));
    m = fmaxf(m, __shfl_xor(m, 4));
    m = fmaxf(m, __shfl_xor(m, 8));
    float s = 0.f;
    #pragma unroll
    for (int p = 0; p < 4; p++) { w4[p] = __expf(w4[p] - m); s += w4[p]; }
    s += __shfl_xor(s, 4);
    s += __shfl_xor(s, 8);
    float inv = 1.f / s;

    const unsigned short* vbase =
        vbf + (((size_t)(((b << 2) + l) * 8 + h)) << 15) + d8 * 8;

    float acc[8];
    #pragma unroll
    for (int k = 0; k < 8; k++) acc[k] = 0.f;

    #pragma unroll
    for (int pp = 0; pp < 2; pp++) {           // 2 points per batch, 8 taps staged
        v8u uv[8];
        float cw[8];
        #pragma unroll
        for (int p2 = 0; p2 < 2; p2++) {
            int p = pp * 2 + p2;
            float xf = locv[p * 2] * 32.f - 0.5f, yf = locv[p * 2 + 1] * 32.f - 0.5f;
            float x0f = floorf(xf), y0f = floorf(yf);
            float fx = xf - x0f, fy = yf - y0f;
            int x0 = (int)x0f, y0 = (int)y0f;
            float wgt = w4[p] * inv;
            #pragma unroll
            for (int dy = 0; dy < 2; dy++) {
                #pragma unroll
                for (int dx = 0; dx < 2; dx++) {
                    int idx = p2 * 4 + dy * 2 + dx;
                    int xi = x0 + dx, yi = y0 + dy;
                    float wt = (dx ? fx : 1.f - fx) * (dy ? fy : 1.f - fy);
                    bool valid = (xi >= 0) & (xi < 32) & (yi >= 0) & (yi < 32);
                    int xc = min(max(xi, 0), 31), yc = min(max(yi, 0), 31);
                    cw[idx] = valid ? (wgt * wt) : 0.f;
                    uv[idx] = *(const v8u*)(vbase + (size_t)((yc << 5) + xc) * 32);
                }
            }
        }
        #pragma unroll
        for (int idx = 0; idx < 8; idx++) {
            float c = cw[idx];
            #pragma unroll
            for (int k = 0; k < 8; k++)
                acc[k] += c * bf2f(uv[idx][k]);
        }
    }
    #pragma unroll
    for (int k = 0; k < 8; k++) {
        acc[k] += __shfl_xor(acc[k], 4);
        acc[k] += __shfl_xor(acc[k], 8);
    }
    if (l == 0) {
        v8u o;
        #pragma unroll
        for (int k = 0; k < 8; k++) o[k] = f2bf(acc[k]);
        *(v8u*)(attn_bf + (size_t)r * 256 + h * 32 + d8 * 8) = o;
    }
}

// ---------------------------------------------------------------------------
// In-place LayerNorm over 256 cols; optional bf16 copy-out.
// ---------------------------------------------------------------------------
template<bool WRITE_BF>
__global__ __launch_bounds__(256) void layernorm_k(
    float* __restrict__ x, const float* __restrict__ g, const float* __restrict__ b,
    unsigned short* __restrict__ xbf)
{
    int lane = threadIdx.x & 63;
    int wv = threadIdx.x >> 6;
    int row = blockIdx.x * 4 + wv;
    int c = lane << 2;
    float4 v = *(const float4*)(x + (size_t)row * 256 + c);
    float s = v.x + v.y + v.z + v.w;
    #pragma unroll
    for (int o = 1; o < 64; o <<= 1) s += __shfl_xor(s, o);
    float mu = s * (1.f / 256.f);
    float d0 = v.x - mu, d1 = v.y - mu, d2 = v.z - mu, d3 = v.w - mu;
    float vs = d0 * d0 + d1 * d1 + d2 * d2 + d3 * d3;
    #pragma unroll
    for (int o = 1; o < 64; o <<= 1) vs += __shfl_xor(vs, o);
    float rstd = rsqrtf(vs * (1.f / 256.f) + 1e-5f);
    float4 gg = *(const float4*)(g + c);
    float4 bb = *(const float4*)(b + c);
    float4 o4;
    o4.x = d0 * rstd * gg.x + bb.x;
    o4.y = d1 * rstd * gg.y + bb.y;
    o4.z = d2 * rstd * gg.z + bb.z;
    o4.w = d3 * rstd * gg.w + bb.w;
    *(float4*)(x + (size_t)row * 256 + c) = o4;
    if (WRITE_BF) {
        ushort4 ob;
        ob.x = f2bf(o4.x); ob.y = f2bf(o4.y); ob.z = f2bf(o4.z); ob.w = f2bf(o4.w);
        *(ushort4*)(xbf + (size_t)row * 256 + c) = ob;
    }
}

// ---------------------------------------------------------------------------
extern "C" void kernel_launch(void* const* d_in, const int* in_sizes, int n_in,
                              void* d_out, int out_size, void* d_ws, size_t ws_size,
                              hipStream_t stream)
{
    const float* src   = (const float*)d_in[0];
    const float* refp  = (const float*)d_in[2];
    const float* vw    = (const float*)d_in[3];
    const float* vb    = (const float*)d_in[4];
    const float* ofw   = (const float*)d_in[5];
    const float* ofb   = (const float*)d_in[6];
    const float* aww   = (const float*)d_in[7];
    const float* awb   = (const float*)d_in[8];
    const float* pw    = (const float*)d_in[9];
    const float* pb    = (const float*)d_in[10];
    const float* g1    = (const float*)d_in[11];
    const float* b1    = (const float*)d_in[12];
    const float* w1    = (const float*)d_in[13];
    const float* bi1   = (const float*)d_in[14];
    const float* w2    = (const float*)d_in[15];
    const float* bi2   = (const float*)d_in[16];
    const float* g2    = (const float*)d_in[17];
    const float* b2    = (const float*)d_in[18];

    float* ws = (float*)d_ws;
    float*          po        = ws;                               // 1,048,576 f
    float*          x1        = ws + 1048576;                     // 2,097,152 f
    unsigned short* value_bf  = (unsigned short*)(ws + 3145728);  // 2,097,152 us
    unsigned short* x1_bf     = (unsigned short*)(ws + 5242880);
    unsigned short* attn_bf   = (unsigned short*)(ws + 6291456);
    unsigned short* hidden_bf = (unsigned short*)(ws + 7340032);  // 8,388,608 us
    unsigned short* Btcat     = (unsigned short*)(ws + 11534336); // 163,840 us
    unsigned short* pwT       = (unsigned short*)(ws + 11616256);
    unsigned short* w1T       = (unsigned short*)(ws + 11649024);
    unsigned short* w2T       = (unsigned short*)(ws + 11780096);
    float*          biascat   = ws + 11911168;                    // 640 f

    float* out_x   = (float*)d_out;
    float* out_loc = out_x + 2097152;

    dim3 blk(256);

    // --- weight prep (bf16, transposed) + biascat ---
    prep_k<<<737, blk, 0, stream>>>(vw, ofw, aww, pw, w1, w2,
                                    Btcat, pwT, w1T, w2T, vb, ofb, awb, biascat);

    // --- fused projections (A converted in-kernel from fp32 src), BN=128
    mfma_gemm128_k<true, true, false, false, false><<<dim3(5, 128), blk, 0, stream>>>(
        src, Btcat, biascat, nullptr, po, value_bf, refp, out_loc, ROWS, 640, 256);

    // --- softmax + deformable gather -> attn_bf
    fused_gather_k<<<4096, blk, 0, stream>>>(po, value_bf, out_loc, attn_bf);

    // --- output projection + residual(src) + LN1 fused -> x1 (fp32+bf16)
    mfma_gemm_ln_k<true><<<256, blk, 0, stream>>>(
        attn_bf, pwT, pb, src, g1, b1, x1, x1_bf, ROWS, 256);

    // --- FFN1: relu(x1 @ w1 + b1) -> hidden_bf, BN=128
    mfma_gemm128_k<false, false, true, true, false><<<dim3(8, 128), blk, 0, stream>>>(
        x1_bf, w1T, bi1, nullptr, hidden_bf, nullptr, nullptr, nullptr, ROWS, 1024, 256);

    // --- FFN2 + residual(x1) -> out_x, then LN2
    mfma_gemm64_k<false, false, true><<<dim3(4, 128), blk, 0, stream>>>(
        hidden_bf, w2T, bi2, x1, out_x, ROWS, 256, 1024);
    layernorm_k<false><<<2048, blk, 0, stream>>>(out_x, g2, b2, nullptr);
}

// Round 20
// 178.873 us; speedup vs baseline: 3.8099x; 1.0171x over previous
//
#include <hip/hip_runtime.h>
#include <math.h>

#define ROWS   8192
#define LQ     4096
#define NHEAD  8
#define NLVL   4
#define NPTS   4
#define HDIM   32

typedef __attribute__((ext_vector_type(8))) short v8s;
typedef __attribute__((ext_vector_type(4))) float v4f;
typedef __attribute__((ext_vector_type(8))) unsigned short v8u;

__device__ __forceinline__ unsigned short f2bf(float x) {
    unsigned int u = __float_as_uint(x);
    u += 0x7fffu + ((u >> 16) & 1u);
    return (unsigned short)(u >> 16);
}
__device__ __forceinline__ float bf2f(unsigned short x) {
    return __uint_as_float(((unsigned int)x) << 16);
}

// async global -> LDS, 16B per lane; LDS dest = wave-uniform base + lane*16
__device__ __forceinline__ void glds16(const void* g, void* l) {
    __builtin_amdgcn_global_load_lds(
        (const __attribute__((address_space(1))) unsigned int*)g,
        (__attribute__((address_space(3))) unsigned int*)l, 16, 0, 0);
}

// ---------------------------------------------------------------------------
// Prep: weight transposes + biascat.
// ---------------------------------------------------------------------------
__device__ __forceinline__ void trans_tile(const float* __restrict__ in,
                                           unsigned short* __restrict__ out,
                                           int K, int N, int ldout, int n_off,
                                           int bx, int by, int tid)
{
    __shared__ float t[32][33];
    int tx = tid & 31, ty = tid >> 5;           // 32 x 8
    int k0 = by << 5, n0 = bx << 5;
    #pragma unroll
    for (int i = 0; i < 4; i++)
        t[ty + i * 8][tx] = in[(size_t)(k0 + ty + i * 8) * N + n0 + tx];
    __syncthreads();
    #pragma unroll
    for (int i = 0; i < 4; i++)
        out[(size_t)(n_off + n0 + ty + i * 8) * ldout + k0 + tx] = f2bf(t[tx][ty + i * 8]);
}

__global__ __launch_bounds__(256) void prep_k(
    const float* __restrict__ vw, const float* __restrict__ ofw,
    const float* __restrict__ aww, const float* __restrict__ pw,
    const float* __restrict__ w1, const float* __restrict__ w2,
    unsigned short* __restrict__ Btcat, unsigned short* __restrict__ pwT,
    unsigned short* __restrict__ w1T, unsigned short* __restrict__ w2T,
    const float* __restrict__ vb, const float* __restrict__ ofb,
    const float* __restrict__ awb, float* __restrict__ biascat)
{
    int bid = blockIdx.x, tid = threadIdx.x;
    if (bid < 64) {                              // vw: 8x8
        int t = bid; trans_tile(vw, Btcat, 256, 256, 256, 0, t & 7, t >> 3, tid);
    } else if (bid < 128) {                      // ofw: 8x8
        int t = bid - 64; trans_tile(ofw, Btcat, 256, 256, 256, 256, t & 7, t >> 3, tid);
    } else if (bid < 160) {                      // aww: 4x8
        int t = bid - 128; trans_tile(aww, Btcat, 256, 128, 256, 512, t & 3, t >> 2, tid);
    } else if (bid < 224) {                      // pw: 8x8
        int t = bid - 160; trans_tile(pw, pwT, 256, 256, 256, 0, t & 7, t >> 3, tid);
    } else if (bid < 480) {                      // w1: 32x8
        int t = bid - 224; trans_tile(w1, w1T, 256, 1024, 256, 0, t & 31, t >> 5, tid);
    } else if (bid < 736) {                      // w2: 8x32
        int t = bid - 480; trans_tile(w2, w2T, 1024, 256, 1024, 0, t & 7, t >> 3, tid);
    } else {                                     // biascat
        biascat[tid] = vb[tid];
        biascat[tid + 256] = ofb[tid];
        if (tid < 128) biascat[tid + 512] = awb[tid];
    }
}

// ---------------------------------------------------------------------------
// bf16 MFMA GEMM, BM=64/BN=128/BK=32. XOR-swizzled glds16 LDS.
// AF32: A fp32 staged with in-register f2bf (1 chunk/thread).
// PROJ (N=640): [0,256) -> compact value bf16; [256,512) -> out_loc;
// [512,640) -> po logits.
// ---------------------------------------------------------------------------
template<bool PROJ, bool AF32, bool OUTBF, bool RELU, bool RES>
__global__ __launch_bounds__(256) void mfma_gemm128_k(
    const void* __restrict__ Araw,          // bf16 or fp32 [M][K]
    const unsigned short* __restrict__ Bt,  // bf16 [N][K]
    const float* __restrict__ bias,
    const float* __restrict__ res,
    void* __restrict__ Cout,
    unsigned short* __restrict__ vbf,       // PROJ only
    const float* __restrict__ refp,         // PROJ only
    float* __restrict__ oloc,               // PROJ only
    int M, int N, int K)
{
    __shared__ __align__(16) unsigned short As[2048];   // 256 chunks x 16B
    __shared__ __align__(16) unsigned short Bs[4096];   // 512 chunks x 16B
    const int tid = threadIdx.x;
    const int row0 = blockIdx.y << 6, col0 = blockIdx.x << 7;
    const int wid = tid >> 6, lane = tid & 63;
    const int wm = wid & 1, wn = wid >> 1;
    const int lr = lane & 15, kq = lane >> 4;

    v4f acc[2][4];
    #pragma unroll
    for (int i = 0; i < 2; i++)
        #pragma unroll
        for (int j = 0; j < 4; j++) acc[i][j] = (v4f){0.f, 0.f, 0.f, 0.f};

    for (int k0 = 0; k0 < K; k0 += 32) {
        float4 af0, af1;
        if constexpr (AF32) {
            const float* Af = (const float*)Araw;
            int r1 = tid >> 2, kk1 = ((tid & 3) + (r1 >> 2)) & 3;
            const float* p1 = Af + (size_t)(row0 + r1) * K + k0 + kk1 * 8;
            af0 = *(const float4*)p1; af1 = *(const float4*)(p1 + 4);
        }
        __syncthreads();
        if constexpr (AF32) {
            v8u u1;
            u1[0] = f2bf(af0.x); u1[1] = f2bf(af0.y); u1[2] = f2bf(af0.z); u1[3] = f2bf(af0.w);
            u1[4] = f2bf(af1.x); u1[5] = f2bf(af1.y); u1[6] = f2bf(af1.z); u1[7] = f2bf(af1.w);
            *(v8u*)(&As[tid * 8]) = u1;
        } else {
            const unsigned short* A = (const unsigned short*)Araw;
            int c = wid * 64 + lane;
            int row = c >> 2;
            int kk = ((c & 3) + (row >> 2)) & 3;
            glds16(A + (size_t)(row0 + row) * K + k0 + kk * 8,
                   &As[(wid * 64) * 8]);
        }
        #pragma unroll
        for (int i = 0; i < 2; i++) {
            int c = wid * 128 + i * 64 + lane;
            int row = c >> 2;
            int kk = ((c & 3) + (row >> 2)) & 3;
            glds16(Bt + (size_t)(col0 + row) * K + k0 + kk * 8,
                   &Bs[(wid * 128 + i * 64) * 8]);
        }
        __syncthreads();
        v8s bf[4];
        #pragma unroll
        for (int nt = 0; nt < 4; nt++) {
            int row = wn * 64 + nt * 16 + lr;
            int s = (kq - (row >> 2)) & 3;
            bf[nt] = *(const v8s*)(&Bs[(row * 4 + s) * 8]);
        }
        #pragma unroll
        for (int mt = 0; mt < 2; mt++) {
            int row = wm * 32 + mt * 16 + lr;
            int s = (kq - (row >> 2)) & 3;
            v8s af = *(const v8s*)(&As[(row * 4 + s) * 8]);
            #pragma unroll
            for (int nt = 0; nt < 4; nt++)
                acc[mt][nt] = __builtin_amdgcn_mfma_f32_16x16x32_bf16(af, bf[nt], acc[mt][nt], 0, 0, 0);
        }
    }

    const int rq = lane >> 4;
    #pragma unroll
    for (int mt = 0; mt < 2; mt++) {
        #pragma unroll
        for (int nt = 0; nt < 4; nt++) {
            int col = col0 + wn * 64 + nt * 16 + lr;
            float bv = bias[col];
            #pragma unroll
            for (int i = 0; i < 4; i++) {
                int row = row0 + wm * 32 + mt * 16 + rq * 4 + i;
                float v = acc[mt][nt][i] + bv;
                if (RELU) v = fmaxf(v, 0.f);
                if (RES)  v += res[(size_t)row * N + col];
                if (PROJ) {
                    if (col < 256) {
                        int b = row >> 12, rb = row & 4095;
                        int l = rb >> 10, pix = rb & 1023;
                        int h = col >> 5, d = col & 31;
                        size_t idx = ((size_t)(((b << 2) + l) * 8 + h) << 15) + (pix << 5) + d;
                        vbf[idx] = f2bf(v);
                    } else if (col < 512) {
                        int colm = col - 256;
                        int l = (colm >> 3) & 3, cc = colm & 1;
                        oloc[(size_t)row * 256 + colm] =
                            refp[(size_t)row * 8 + l * 2 + cc] + v * (1.f / 32.f);
                    } else {
                        ((float*)Cout)[(size_t)row * 128 + col - 512] = v;
                    }
                } else if (OUTBF) {
                    ((unsigned short*)Cout)[(size_t)row * N + col] = f2bf(v);
                } else {
                    ((float*)Cout)[(size_t)row * N + col] = v;
                }
            }
        }
    }
}

// ---------------------------------------------------------------------------
// bf16 MFMA GEMM, BM=64/BN=64/BK=32 — FFN2 (N=256), 512 blocks (2/CU).
// RESBF: residual read from bf16 buffer (x1_bf) instead of fp32.
// ---------------------------------------------------------------------------
template<bool OUTBF, bool RELU, bool RESBF>
__global__ __launch_bounds__(256) void mfma_gemm64_k(
    const unsigned short* __restrict__ A,   // bf16 [M][K]
    const unsigned short* __restrict__ Bt,  // bf16 [N][K]
    const float* __restrict__ bias,
    const unsigned short* __restrict__ resbf,
    void* __restrict__ Cout,
    int M, int N, int K)
{
    __shared__ __align__(16) unsigned short As[2048];   // 256 chunks x 16B
    __shared__ __align__(16) unsigned short Bs[2048];   // 256 chunks x 16B
    const int tid = threadIdx.x;
    const int row0 = blockIdx.y << 6, col0 = blockIdx.x << 6;
    const int wid = tid >> 6, lane = tid & 63;
    const int lr = lane & 15, kq = lane >> 4;

    v4f acc[4];
    #pragma unroll
    for (int i = 0; i < 4; i++) acc[i] = (v4f){0.f, 0.f, 0.f, 0.f};

    for (int k0 = 0; k0 < K; k0 += 32) {
        __syncthreads();
        {
            int c = wid * 64 + lane;
            int row = c >> 2;
            int kk = ((c & 3) + (row >> 2)) & 3;
            glds16(A + (size_t)(row0 + row) * K + k0 + kk * 8, &As[wid * 512]);
            glds16(Bt + (size_t)(col0 + row) * K + k0 + kk * 8, &Bs[wid * 512]);
        }
        __syncthreads();
        int colr = wid * 16 + lr;
        int sb = (kq - (colr >> 2)) & 3;
        v8s bf = *(const v8s*)(&Bs[(colr * 4 + sb) * 8]);
        #pragma unroll
        for (int mt = 0; mt < 4; mt++) {
            int rowr = mt * 16 + lr;
            int sa = (kq - (rowr >> 2)) & 3;
            v8s af = *(const v8s*)(&As[(rowr * 4 + sa) * 8]);
            acc[mt] = __builtin_amdgcn_mfma_f32_16x16x32_bf16(af, bf, acc[mt], 0, 0, 0);
        }
    }

    const int rq = lane >> 4;
    const int col = col0 + wid * 16 + lr;
    float bv = bias[col];
    #pragma unroll
    for (int mt = 0; mt < 4; mt++) {
        #pragma unroll
        for (int i = 0; i < 4; i++) {
            int row = row0 + mt * 16 + rq * 4 + i;
            float v = acc[mt][i] + bv;
            if (RELU) v = fmaxf(v, 0.f);
            if (RESBF) v += bf2f(resbf[(size_t)row * N + col]);
            if (OUTBF) ((unsigned short*)Cout)[(size_t)row * N + col] = f2bf(v);
            else       ((float*)Cout)[(size_t)row * N + col] = v;
        }
    }
}

// ---------------------------------------------------------------------------
// Full-row GEMM + residual + LayerNorm fused epilogue (outproj).
// Writes bf16 post-LN only (x1_bf); fp32 x1 no longer materialized.
// ---------------------------------------------------------------------------
__global__ __launch_bounds__(256) void mfma_gemm_ln_k(
    const unsigned short* __restrict__ A,   // bf16 [M][K]
    const unsigned short* __restrict__ Bt,  // bf16 [256][K]
    const float* __restrict__ bias,         // [256]
    const float* __restrict__ res,          // [M][256] fp32
    const float* __restrict__ g,
    const float* __restrict__ b,
    unsigned short* __restrict__ outbf,     // bf16 post-LN
    int M, int K)
{
    __shared__ __align__(16) unsigned short As[1024];   // 128 chunks x 16B
    __shared__ __align__(16) unsigned short Bs[8192];   // 1024 chunks x 16B
    __shared__ float red[2][32][4];
    const int tid = threadIdx.x;
    const int row0 = blockIdx.x << 5;
    const int wid = tid >> 6, lane = tid & 63;
    const int lr = lane & 15, kq = lane >> 4;
    const int rq = kq;

    v4f acc[2][4];
    #pragma unroll
    for (int i = 0; i < 2; i++)
        #pragma unroll
        for (int j = 0; j < 4; j++) acc[i][j] = (v4f){0.f, 0.f, 0.f, 0.f};

    for (int k0 = 0; k0 < K; k0 += 32) {
        __syncthreads();
        if (wid < 2) {                          // A: 128 chunks
            int c = wid * 64 + lane;
            int row = c >> 2;
            int kk = ((c & 3) + (row >> 2)) & 3;
            glds16(A + (size_t)(row0 + row) * K + k0 + kk * 8,
                   &As[(wid * 64) * 8]);
        }
        #pragma unroll
        for (int i = 0; i < 4; i++) {           // B: 1024 chunks
            int c = (wid * 4 + i) * 64 + lane;
            int col = c >> 2;
            int kk = ((c & 3) + (col >> 2)) & 3;
            glds16(Bt + (size_t)col * K + k0 + kk * 8,
                   &Bs[((wid * 4 + i) * 64) * 8]);
        }
        __syncthreads();
        v8s bf[4];
        #pragma unroll
        for (int ct = 0; ct < 4; ct++) {
            int col = wid * 64 + ct * 16 + lr;
            int s = (kq - (col >> 2)) & 3;
            bf[ct] = *(const v8s*)(&Bs[(col * 4 + s) * 8]);
        }
        #pragma unroll
        for (int rt = 0; rt < 2; rt++) {
            int rowl = rt * 16 + lr;
            int s = (kq - (rowl >> 2)) & 3;
            v8s af = *(const v8s*)(&As[(rowl * 4 + s) * 8]);
            #pragma unroll
            for (int ct = 0; ct < 4; ct++)
                acc[rt][ct] = __builtin_amdgcn_mfma_f32_16x16x32_bf16(af, bf[ct], acc[rt][ct], 0, 0, 0);
        }
    }

    float t[2][4][4];
    float s1[2][4], s2[2][4];
    #pragma unroll
    for (int rt = 0; rt < 2; rt++)
        #pragma unroll
        for (int i = 0; i < 4; i++) { s1[rt][i] = 0.f; s2[rt][i] = 0.f; }
    #pragma unroll
    for (int rt = 0; rt < 2; rt++) {
        #pragma unroll
        for (int ct = 0; ct < 4; ct++) {
            int col = wid * 64 + ct * 16 + lr;
            float bv = bias[col];
            #pragma unroll
            for (int i = 0; i < 4; i++) {
                int row = row0 + rt * 16 + rq * 4 + i;
                float v = acc[rt][ct][i] + bv + res[(size_t)row * 256 + col];
                t[rt][ct][i] = v;
                s1[rt][i] += v;
                s2[rt][i] += v * v;
            }
        }
    }
    #pragma unroll
    for (int o = 1; o < 16; o <<= 1) {
        #pragma unroll
        for (int rt = 0; rt < 2; rt++)
            #pragma unroll
            for (int i = 0; i < 4; i++) {
                s1[rt][i] += __shfl_xor(s1[rt][i], o);
                s2[rt][i] += __shfl_xor(s2[rt][i], o);
            }
    }
    if (lr == 0) {
        #pragma unroll
        for (int rt = 0; rt < 2; rt++)
            #pragma unroll
            for (int i = 0; i < 4; i++) {
                int rl = rt * 16 + rq * 4 + i;
                red[0][rl][wid] = s1[rt][i];
                red[1][rl][wid] = s2[rt][i];
            }
    }
    __syncthreads();
    float mu[2][4], rstd[2][4];
    #pragma unroll
    for (int rt = 0; rt < 2; rt++) {
        #pragma unroll
        for (int i = 0; i < 4; i++) {
            int rl = rt * 16 + rq * 4 + i;
            float S1 = red[0][rl][0] + red[0][rl][1] + red[0][rl][2] + red[0][rl][3];
            float S2 = red[1][rl][0] + red[1][rl][1] + red[1][rl][2] + red[1][rl][3];
            float m = S1 * (1.f / 256.f);
            mu[rt][i] = m;
            rstd[rt][i] = rsqrtf(S2 * (1.f / 256.f) - m * m + 1e-5f);
        }
    }
    #pragma unroll
    for (int rt = 0; rt < 2; rt++) {
        #pragma unroll
        for (int ct = 0; ct < 4; ct++) {
            int col = wid * 64 + ct * 16 + lr;
            float gg = g[col], bb = b[col];
            #pragma unroll
            for (int i = 0; i < 4; i++) {
                int row = row0 + rt * 16 + rq * 4 + i;
                float o = (t[rt][ct][i] - mu[rt][i]) * rstd[rt][i] * gg + bb;
                outbf[(size_t)row * 256 + col] = f2bf(o);
            }
        }
    }
}

// ---------------------------------------------------------------------------
// Fused gather, level-split, 16B taps (R16-proven). XCD-aware h.
// ---------------------------------------------------------------------------
__global__ __launch_bounds__(256) void fused_gather_k(
    const float* __restrict__ po,              // [ROWS][128] logits
    const unsigned short* __restrict__ vbf,    // [64][1024][32] bf16
    const float* __restrict__ loc,             // [ROWS][256] sampling locs
    unsigned short* __restrict__ attn_bf)      // [ROWS][256] bf16
{
    int tid = threadIdx.x;
    int g = tid >> 4, l = (tid >> 2) & 3, d8 = tid & 3;
    int h = blockIdx.x & 7;                    // XCD-aligned head
    int r = (blockIdx.x >> 3) * 16 + g;
    int b = r >> 12;

    float locv[8];
    *(float4*)(locv)     = *(const float4*)(loc + (size_t)r * 256 + h * 32 + l * 8);
    *(float4*)(locv + 4) = *(const float4*)(loc + (size_t)r * 256 + h * 32 + l * 8 + 4);

    float w4[4];
    *(float4*)(w4) = *(const float4*)(po + (size_t)r * 128 + h * 16 + l * 4);
    float m = fmaxf(fmaxf(w4[0], w4[1]), fmaxf(w4[2], w4[3]));
    m = fmaxf(m, __shfl_xor(m, 4));
    m = fmaxf(m, __shfl_xor(m, 8));
    float s = 0.f;
    #pragma unroll
    for (int p = 0; p < 4; p++) { w4[p] = __expf(w4[p] - m); s += w4[p]; }
    s += __shfl_xor(s, 4);
    s += __shfl_xor(s, 8);
    float inv = 1.f / s;

    const unsigned short* vbase =
        vbf + (((size_t)(((b << 2) + l) * 8 + h)) << 15) + d8 * 8;

    float acc[8];
    #pragma unroll
    for (int k = 0; k < 8; k++) acc[k] = 0.f;

    #pragma unroll
    for (int pp = 0; pp < 2; pp++) {           // 2 points per batch, 8 taps staged
        v8u uv[8];
        float cw[8];
        #pragma unroll
        for (int p2 = 0; p2 < 2; p2++) {
            int p = pp * 2 + p2;
            float xf = locv[p * 2] * 32.f - 0.5f, yf = locv[p * 2 + 1] * 32.f - 0.5f;
            float x0f = floorf(xf), y0f = floorf(yf);
            float fx = xf - x0f, fy = yf - y0f;
            int x0 = (int)x0f, y0 = (int)y0f;
            float wgt = w4[p] * inv;
            #pragma unroll
            for (int dy = 0; dy < 2; dy++) {
                #pragma unroll
                for (int dx = 0; dx < 2; dx++) {
                    int idx = p2 * 4 + dy * 2 + dx;
                    int xi = x0 + dx, yi = y0 + dy;
                    float wt = (dx ? fx : 1.f - fx) * (dy ? fy : 1.f - fy);
                    bool valid = (xi >= 0) & (xi < 32) & (yi >= 0) & (yi < 32);
                    int xc = min(max(xi, 0), 31), yc = min(max(yi, 0), 31);
                    cw[idx] = valid ? (wgt * wt) : 0.f;
                    uv[idx] = *(const v8u*)(vbase + (size_t)((yc << 5) + xc) * 32);
                }
            }
        }
        #pragma unroll
        for (int idx = 0; idx < 8; idx++) {
            float c = cw[idx];
            #pragma unroll
            for (int k = 0; k < 8; k++)
                acc[k] += c * bf2f(uv[idx][k]);
        }
    }
    #pragma unroll
    for (int k = 0; k < 8; k++) {
        acc[k] += __shfl_xor(acc[k], 4);
        acc[k] += __shfl_xor(acc[k], 8);
    }
    if (l == 0) {
        v8u o;
        #pragma unroll
        for (int k = 0; k < 8; k++) o[k] = f2bf(acc[k]);
        *(v8u*)(attn_bf + (size_t)r * 256 + h * 32 + d8 * 8) = o;
    }
}

// ---------------------------------------------------------------------------
// In-place LayerNorm over 256 cols.
// ---------------------------------------------------------------------------
__global__ __launch_bounds__(256) void layernorm_k(
    float* __restrict__ x, const float* __restrict__ g, const float* __restrict__ b)
{
    int lane = threadIdx.x & 63;
    int wv = threadIdx.x >> 6;
    int row = blockIdx.x * 4 + wv;
    int c = lane << 2;
    float4 v = *(const float4*)(x + (size_t)row * 256 + c);
    float s = v.x + v.y + v.z + v.w;
    #pragma unroll
    for (int o = 1; o < 64; o <<= 1) s += __shfl_xor(s, o);
    float mu = s * (1.f / 256.f);
    float d0 = v.x - mu, d1 = v.y - mu, d2 = v.z - mu, d3 = v.w - mu;
    float vs = d0 * d0 + d1 * d1 + d2 * d2 + d3 * d3;
    #pragma unroll
    for (int o = 1; o < 64; o <<= 1) vs += __shfl_xor(vs, o);
    float rstd = rsqrtf(vs * (1.f / 256.f) + 1e-5f);
    float4 gg = *(const float4*)(g + c);
    float4 bb = *(const float4*)(b + c);
    float4 o4;
    o4.x = d0 * rstd * gg.x + bb.x;
    o4.y = d1 * rstd * gg.y + bb.y;
    o4.z = d2 * rstd * gg.z + bb.z;
    o4.w = d3 * rstd * gg.w + bb.w;
    *(float4*)(x + (size_t)row * 256 + c) = o4;
}

// ---------------------------------------------------------------------------
extern "C" void kernel_launch(void* const* d_in, const int* in_sizes, int n_in,
                              void* d_out, int out_size, void* d_ws, size_t ws_size,
                              hipStream_t stream)
{
    const float* src   = (const float*)d_in[0];
    const float* refp  = (const float*)d_in[2];
    const float* vw    = (const float*)d_in[3];
    const float* vb    = (const float*)d_in[4];
    const float* ofw   = (const float*)d_in[5];
    const float* ofb   = (const float*)d_in[6];
    const float* aww   = (const float*)d_in[7];
    const float* awb   = (const float*)d_in[8];
    const float* pw    = (const float*)d_in[9];
    const float* pb    = (const float*)d_in[10];
    const float* g1    = (const float*)d_in[11];
    const float* b1    = (const float*)d_in[12];
    const float* w1    = (const float*)d_in[13];
    const float* bi1   = (const float*)d_in[14];
    const float* w2    = (const float*)d_in[15];
    const float* bi2   = (const float*)d_in[16];
    const float* g2    = (const float*)d_in[17];
    const float* b2    = (const float*)d_in[18];

    float* ws = (float*)d_ws;
    float*          po        = ws;                               // 1,048,576 f
    unsigned short* value_bf  = (unsigned short*)(ws + 1048576);  // 2,097,152 us
    unsigned short* x1_bf     = (unsigned short*)(ws + 2097152);
    unsigned short* attn_bf   = (unsigned short*)(ws + 3145728);
    unsigned short* hidden_bf = (unsigned short*)(ws + 4194304);  // 8,388,608 us
    unsigned short* Btcat     = (unsigned short*)(ws + 8388608);  // 163,840 us
    unsigned short* pwT       = (unsigned short*)(ws + 8470528);
    unsigned short* w1T       = (unsigned short*)(ws + 8503296);
    unsigned short* w2T       = (unsigned short*)(ws + 8634368);
    float*          biascat   = ws + 8765440;                     // 640 f

    float* out_x   = (float*)d_out;
    float* out_loc = out_x + 2097152;

    dim3 blk(256);

    // --- weight prep (bf16, transposed) + biascat ---
    prep_k<<<737, blk, 0, stream>>>(vw, ofw, aww, pw, w1, w2,
                                    Btcat, pwT, w1T, w2T, vb, ofb, awb, biascat);

    // --- fused projections (A converted in-kernel from fp32 src), BN=128
    mfma_gemm128_k<true, true, false, false, false><<<dim3(5, 128), blk, 0, stream>>>(
        src, Btcat, biascat, nullptr, po, value_bf, refp, out_loc, ROWS, 640, 256);

    // --- softmax + deformable gather -> attn_bf
    fused_gather_k<<<4096, blk, 0, stream>>>(po, value_bf, out_loc, attn_bf);

    // --- output projection + residual(src) + LN1 fused -> x1_bf only
    mfma_gemm_ln_k<<<256, blk, 0, stream>>>(
        attn_bf, pwT, pb, src, g1, b1, x1_bf, ROWS, 256);

    // --- FFN1: relu(x1 @ w1 + b1) -> hidden_bf, BN=128
    mfma_gemm128_k<false, false, true, true, false><<<dim3(8, 128), blk, 0, stream>>>(
        x1_bf, w1T, bi1, nullptr, hidden_bf, nullptr, nullptr, nullptr, ROWS, 1024, 256);

    // --- FFN2 + residual(x1_bf) -> out_x, then LN2
    mfma_gemm64_k<false, false, true><<<dim3(4, 128), blk, 0, stream>>>(
        hidden_bf, w2T, bi2, x1_bf, out_x, ROWS, 256, 1024);
    layernorm_k<<<2048, blk, 0, stream>>>(out_x, g2, b2);
}